// Round 18
// baseline (2163.353 us; speedup 1.0000x reference)
//
#include <hip/hip_runtime.h>
#include <hip/hip_bf16.h>

#define N_LAYERS 1000
#define DD 100
#define DOUT 10
#define FRAG 4096                 // bytes per (layer,ks) fragment: 4 groups * 64 lanes * 16B
#define LBYTES (7 * FRAG)         // 28672 B per layer
#define NROWS 65536

typedef short s8v __attribute__((ext_vector_type(8)));
typedef float f16v __attribute__((ext_vector_type(16)));
typedef float f4v __attribute__((ext_vector_type(4)));

__device__ __forceinline__ unsigned short f2bf(float f) {
  __hip_bfloat16 h = __float2bfloat16(f);   // HW RNE
  return *reinterpret_cast<unsigned short*>(&h);
}
__device__ __forceinline__ float bf2f(unsigned short h) {
  return __uint_as_float(((unsigned)h) << 16);
}
__device__ __forceinline__ unsigned pk2(float a, float b) {  // packed bf16 pair (RNE)
  return (unsigned)f2bf(a) | ((unsigned)f2bf(b) << 16);
}

// ---------------- prologue: W (f32) + bias -> lane-packed bf16 fragments, ks-contiguous ----
// byte off = (L*7+ks)*4096 + gf*1024 + lane*16
// frag (gf,lane): n = gf*32+(lane&31), k = ks*16+(lane>>5)*8+j ; k==100 holds bias; pads 0.
__global__ __launch_bounds__(256)
void presplit_kernel(const float* __restrict__ W, const float* __restrict__ b,
                     char* __restrict__ hi_g) {
  int idx = blockIdx.x * 256 + threadIdx.x;
  if (idx >= N_LAYERS * 7 * 4 * 64) return;
  int lane = idx & 63;
  int gf = (idx >> 6) & 3;
  int r = idx >> 8;          // L*7 + ks
  int ks = r % 7;
  int L = r / 7;
  int n = gf * 32 + (lane & 31);
  int k0 = ks * 16 + (lane >> 5) * 8;
  s8v hv;
#pragma unroll
  for (int j = 0; j < 8; ++j) {
    int k = k0 + j;
    float v = 0.0f;
    if (n < DD) {
      if (k < DD) v = W[((size_t)L * DD + n) * DD + k];
      else if (k == DD) v = b[(size_t)L * DD + n];
    }
    hv[j] = (short)f2bf(v);
  }
  *(s8v*)(hi_g + (size_t)idx * 16) = hv;
}

// fallback: convert one staging chunk (ks=c) from raw f32; thread (wv,lane) covers
// n = wv*32+(lane&31), k = c*16+(lane>>5)*8+j  (identical to packed layout)
__device__ __forceinline__ s8v wconv(int L, int c, int wv, int l31, int lhi,
                                     const float* __restrict__ W_g,
                                     const float* __restrict__ b_g) {
  int n = wv * 32 + l31;
  int k0 = c * 16 + lhi * 8;
  s8v hv;
#pragma unroll
  for (int j = 0; j < 8; ++j) {
    int k = k0 + j;
    float v = 0.0f;
    if (n < DD) {
      if (k < DD) v = W_g[((size_t)L * DD + n) * DD + k];
      else if (k == DD) v = b_g[(size_t)L * DD + n];
    }
    hv[j] = (short)f2bf(v);
  }
  return hv;
}

// ---------------- main kernel: 512 wgs x 256 thr (4 waves), 2 wgs/CU --------------------
// Wave owns 32 batch rows x all 128 padded channels; act fully in registers (r17-proven
// permlane rebuild). W staged per-wg through double-buffered LDS (T14 split: global->reg
// early, ds_write late) -> W VMEM per CU drops 4x vs r17. One barrier per layer.
// Residual xr: f32 quads in global scratch (slot = (q16*2+lhi), coalesced by row).
template <int PRE>
__global__ __launch_bounds__(256, 2)
void resnet_main(const float* __restrict__ x_g,
                 const float* __restrict__ W_g, const float* __restrict__ b_g,
                 const float* __restrict__ Wf_g, const float* __restrict__ bf_g,
                 float* __restrict__ out_g,
                 const char* __restrict__ whi_g, char* __restrict__ xr_g) {
  __shared__ char wbuf[2 * LBYTES];   // 57344 B -> 2 wgs/CU

  const int tid = threadIdx.x;
  const int lane = tid & 63;
  const int wv = tid >> 6;
  const int l31 = lane & 31;
  const int lhi = lane >> 5;
  const int row = blockIdx.x * 128 + wv * 32 + l31;   // this thread's batch row

  // ---- initial B-fragments straight from x (bf16, bias col 1.0, pads 0) ----
  s8v bf[7];
#pragma unroll
  for (int ks = 0; ks < 7; ++ks) {
    const int k0 = ks * 16 + lhi * 8;
    unsigned w[4];
#pragma unroll
    for (int p = 0; p < 4; ++p) {
      const int ka = k0 + 2 * p, kb = k0 + 2 * p + 1;
      float a0 = (ka < DD) ? x_g[(size_t)row * DD + ka] : (ka == DD ? 1.0f : 0.0f);
      float a1 = (kb < DD) ? x_g[(size_t)row * DD + kb] : (kb == DD ? 1.0f : 0.0f);
      w[p] = pk2(a0, a1);
    }
    union { s8v v; unsigned u[4]; } t;
    t.u[0] = w[0]; t.u[1] = w[1]; t.u[2] = w[2]; t.u[3] = w[3];
    bf[ks] = t.v;
  }

  // ---- residual xr init: quads q16=0..12 with channel base < DD -> scratch (PRE) / regs ----
  f4v xrr[13];   // register fallback (PRE==0 only; dead for PRE==1)
#pragma unroll
  for (int q16 = 0; q16 <= 12; ++q16) {
    const int c0 = 32 * (q16 >> 2) + 8 * (q16 & 3) + 4 * lhi;
    if (c0 < DD) {
      f4v xq;
#pragma unroll
      for (int j = 0; j < 4; ++j) {
        int c = c0 + j;
        xq[j] = (c < DD) ? x_g[(size_t)row * DD + c] : 0.0f;
      }
      if (PRE) *(f4v*)(xr_g + ((size_t)(q16 * 2 + lhi) * NROWS + row) * 16) = xq;
      else xrr[q16] = xq;
    }
  }

  // ---- stage layer 0 into wbuf[0] ----
#pragma unroll
  for (int c = 0; c < 7; ++c) {
    s8v v;
    if (PRE) v = *(const s8v*)(whi_g + c * FRAG + tid * 16);
    else     v = wconv(0, c, wv, l31, lhi, W_g, b_g);
    *(s8v*)(&wbuf[c * FRAG + tid * 16]) = v;
  }
  __syncthreads();

  f16v zro;
#pragma unroll
  for (int r = 0; r < 16; ++r) zro[r] = 0.0f;

  int cur = 0;
  for (int L = 0; L < N_LAYERS; ++L) {
    const bool more = (L + 1 < N_LAYERS);

    // ---- issue next-layer staging loads early (T14: land under this layer's compute) ----
    s8v stg[7];
    if (more) {
      if (PRE) {
        const char* ps = whi_g + (size_t)(L + 1) * LBYTES + tid * 16;
#pragma unroll
        for (int c = 0; c < 7; ++c) stg[c] = *(const s8v*)(ps + c * FRAG);
      } else {
#pragma unroll
        for (int c = 0; c < 7; ++c) stg[c] = wconv(L + 1, c, wv, l31, lhi, W_g, b_g);
      }
    }

    // ---- compute from wbuf[cur]: W frags via LDS (all-immediate offsets), depth-2 regs ----
    const char* rb = &wbuf[cur * LBYTES] + lane * 16;
    s8v wr[2][4];
#pragma unroll
    for (int g = 0; g < 4; ++g) wr[0][g] = *(const s8v*)(rb + g * 1024);
    f16v acc[4];
#pragma unroll
    for (int ks = 0; ks < 7; ++ks) {
      const int s = ks & 1;
      if (ks < 6) {
#pragma unroll
        for (int g = 0; g < 4; ++g)
          wr[s ^ 1][g] = *(const s8v*)(rb + (ks + 1) * FRAG + g * 1024);
      }
      if (ks == 0) {
#pragma unroll
        for (int g = 0; g < 4; ++g)
          acc[g] = __builtin_amdgcn_mfma_f32_32x32x16_bf16(wr[0][g], bf[0], zro, 0, 0, 0);
      } else {
#pragma unroll
        for (int g = 0; g < 4; ++g)
          acc[g] = __builtin_amdgcn_mfma_f32_32x32x16_bf16(wr[s][g], bf[ks], acc[g], 0, 0, 0);
      }
    }

    // ---- fused epilogue: relu (+xr at block end) -> cvt_pk -> permlane rebuild (r17-proven) ----
    const bool bend = ((L % 10) == 9);
#pragma unroll
    for (int ks = 0; ks < 7; ++ks) {
      const int g = ks >> 1, qa = 2 * (ks & 1);
      unsigned pa[2], pb[2];
#pragma unroll
      for (int t = 0; t < 2; ++t) {
        const int q = qa + t;
        float o0 = fmaxf(acc[g][4 * q + 0], 0.0f);
        float o1 = fmaxf(acc[g][4 * q + 1], 0.0f);
        float o2 = fmaxf(acc[g][4 * q + 2], 0.0f);
        float o3 = fmaxf(acc[g][4 * q + 3], 0.0f);
        if (bend) {
          const int q16 = g * 4 + q;
          const int c0 = 32 * g + 8 * q + 4 * lhi;
          if (c0 < DD) {
            if (PRE) {
              char* xp = xr_g + ((size_t)(q16 * 2 + lhi) * NROWS + row) * 16;
              f4v xq = *(const f4v*)xp;
              o0 += xq[0]; o1 += xq[1]; o2 += xq[2]; o3 += xq[3];
              f4v nv; nv[0] = o0; nv[1] = o1; nv[2] = o2; nv[3] = o3;
              *(f4v*)xp = nv;
            } else {
              f4v xq = xrr[q16];
              o0 += xq[0]; o1 += xq[1]; o2 += xq[2]; o3 += xq[3];
              f4v nv; nv[0] = o0; nv[1] = o1; nv[2] = o2; nv[3] = o3;
              xrr[q16] = nv;
            }
          }
        }
        pa[t] = pk2(o0, o1); pb[t] = pk2(o2, o3);
      }
      auto rA = __builtin_amdgcn_permlane32_swap((int)pa[0], (int)pa[1], false, false);
      auto rB = __builtin_amdgcn_permlane32_swap((int)pb[0], (int)pb[1], false, false);
      union { s8v v; unsigned u[4]; } t2;
      t2.u[0] = (unsigned)rA[0];
      t2.u[1] = (unsigned)rB[0];
      t2.u[2] = (ks == 6) ? 0x3F80u : (unsigned)rA[1];   // bias column act[100]=1.0
      t2.u[3] = (unsigned)rB[1];
      bf[ks] = t2.v;
    }

    // ---- late ds_write of staged W into wbuf[cur^1] (buffer free since L-1's barrier) ----
    if (more) {
      char* wd = &wbuf[(cur ^ 1) * LBYTES] + tid * 16;
#pragma unroll
      for (int c = 0; c < 7; ++c) *(s8v*)(wd + c * FRAG) = stg[c];
    }
    __syncthreads();   // publishes wbuf[cur^1]; all reads of wbuf[cur] complete
    cur ^= 1;
  }

  // ---- final projection: out = act @ Wf^T + bf ----
  __syncthreads();                       // wbuf dead; reuse for Wf broadcast
  float* xsf = (float*)wbuf;
  for (int i = tid; i < DOUT * DD; i += 256) xsf[i] = Wf_g[i];
  __syncthreads();

  float part[DOUT];
#pragma unroll
  for (int o = 0; o < DOUT; ++o) part[o] = 0.0f;
#pragma unroll
  for (int ks = 0; ks < 7; ++ks) {
#pragma unroll
    for (int j = 0; j < 8; ++j) {
      const int k = ks * 16 + lhi * 8 + j;
      if (k < DD) {
        float a = bf2f((unsigned short)bf[ks][j]);
#pragma unroll
        for (int o = 0; o < DOUT; ++o) part[o] += a * xsf[o * DD + k];
      }
    }
  }
#pragma unroll
  for (int o = 0; o < DOUT; ++o) part[o] += __shfl_xor(part[o], 32);
  if (lhi == 0) {
#pragma unroll
    for (int o = 0; o < DOUT; ++o)
      out_g[(size_t)row * DOUT + o] = part[o] + bf_g[o];
  }
}

extern "C" void kernel_launch(void* const* d_in, const int* in_sizes, int n_in,
                              void* d_out, int out_size, void* d_ws, size_t ws_size,
                              hipStream_t stream) {
  const float* x = (const float*)d_in[0];
  const float* W = (const float*)d_in[1];
  const float* b = (const float*)d_in[2];
  const float* Wf = (const float*)d_in[3];
  const float* bf = (const float*)d_in[4];
  float* out = (float*)d_out;

  const size_t wpack = (size_t)N_LAYERS * LBYTES;        // 28.672 MB
  const size_t xrbytes = (size_t)25 * NROWS * 16;        // 26.214 MB (slots 0..24)
  const size_t need = wpack + xrbytes;                   // 54.886 MB
  const int nwg = 65536 / 128;                           // 512 = 2/CU x 256 CUs, one round
  if (ws_size >= need) {
    char* whi = (char*)d_ws;
    char* xr = whi + wpack;
    const int chunks = N_LAYERS * 7 * 4 * 64;            // 1,792,000
    presplit_kernel<<<(chunks + 255) / 256, 256, 0, stream>>>(W, b, whi);
    resnet_main<1><<<nwg, 256, 0, stream>>>(x, W, b, Wf, bf, out, whi, xr);
  } else {
    resnet_main<0><<<nwg, 256, 0, stream>>>(x, W, b, Wf, bf, out, nullptr, nullptr);
  }
}